// Round 8
// baseline (27395.563 us; speedup 1.0000x reference)
//
#include <hip/hip_runtime.h>

// 2-layer GRU, I=8, H=128, T=32768 sequential steps, out = final h1 (128 f32).
// LAUNCH-LEVEL pipeline (no flags, no spins): launch k runs, as disjoint blocks,
//   block 0   : layer-0 recurrence, chunk k        (writes h0[chunk k])
//   blocks2-4 : gi1 = w_ih1@h0 + b_ih1, chunk k-1  (reads h0, writes gi1 ring)
//   block 1   : layer-1 recurrence, chunk k-2      (reads gi1 ring, writes out)
// Stream order between launches = implicit release/acquire; zero deadlock surface.
// r7 lesson (1605 cy/step): LDS return-BW bound — 64 ds_read_b128/step at 8
// waves. This round: 256 threads, R=6 rows/thread (2 units) -> 32 reads/step,
// 1 wave/SIMD (no issue contention), 4-wave barrier. FMA-issue floor invariant.

#define T_STEPS 32768
#define HDIM 128
#define GS 8
#define CH 1024                 // steps per chunk
#define NC (T_STEPS / CH)       // 32 chunks
#define NGRP (CH / GS)          // groups per chunk

typedef __attribute__((ext_vector_type(2))) float f32x2;
typedef __attribute__((ext_vector_type(4))) float f32x4;

__device__ __forceinline__ f32x2 lo2(f32x4 v) { return __builtin_shufflevector(v, v, 0, 1); }
__device__ __forceinline__ f32x2 hi2(f32x4 v) { return __builtin_shufflevector(v, v, 2, 3); }
__device__ __forceinline__ void pkfma(f32x2& acc, f32x2 a, f32x2 b) {
  asm("v_pk_fma_f32 %0, %1, %2, %0" : "+v"(acc) : "v"(a), "v"(b));
}
__device__ __forceinline__ float sigm(float x) {
  return __fdividef(1.f, 1.f + __expf(-x));
}
__device__ __forceinline__ float tanh_fast(float x) {
  x = fminf(15.f, fmaxf(-15.f, x));
  float e = __expf(2.f * x);
  return (e - 1.f) * __fdividef(1.f, e + 1.f);
}
// quad butterfly (xor1 then xor2 via DPP quad_perm); proven r6/r7 (absmax 0.0)
__device__ __forceinline__ float red4q(float v) {
  int t = __builtin_amdgcn_mov_dpp(__builtin_bit_cast(int, v), 0xB1, 0xF, 0xF, true);
  v += __builtin_bit_cast(float, t);
  t = __builtin_amdgcn_mov_dpp(__builtin_bit_cast(int, v), 0x4E, 0xF, 0xF, true);
  v += __builtin_bit_cast(float, t);
  return v;
}
// Pinned loads: asm results cannot be rematerialized -> stay in VGPRs.
__device__ __forceinline__ f32x4 ld4_pin(const float* p) {
  f32x4 v;
  asm volatile("global_load_dwordx4 %0, %1, off" : "=v"(v) : "v"(p));
  return v;
}
__device__ __forceinline__ f32x2 ld2_pin(const float* p) {
  f32x2 v;
  asm volatile("global_load_dwordx2 %0, %1, off" : "=v"(v) : "v"(p));
  return v;
}
__device__ __forceinline__ float ld1_pin(const float* p) {
  float v;
  asm volatile("global_load_dword %0, %1, off" : "=v"(v) : "v"(p));
  return v;
}
__device__ __forceinline__ void vwait() {
  asm volatile("s_waitcnt vmcnt(0)" ::: "memory");
}

// Thread t (256/block): q=t&3 (32-col chunk), u=t>>2 in [0,64) -> units u, u+64.
// Weights PRE-ROTATED: slot r holds quad k=r^2q -> 4 q-lanes hit 4 disjoint
// bank-quads per read (broadcast across unit-groups), conflict-free (PMC=0).
__device__ __forceinline__ void load_w3_pin(const float* __restrict__ W, int row0,
                                            int q, f32x4 (&w0)[8], f32x4 (&w1)[8],
                                            f32x4 (&w2)[8]) {
  #pragma unroll
  for (int r = 0; r < 8; ++r) {
    const int k = r ^ (q << 1);
    const int col = 32 * q + 4 * k;
    w0[r] = ld4_pin(W + (size_t)row0 * 128 + col);
    w1[r] = ld4_pin(W + (size_t)(row0 + 128) * 128 + col);
    w2[r] = ld4_pin(W + (size_t)(row0 + 256) * 128 + col);
  }
}

// h-part for 6 rows (2 units x 3 gates): each h4 read feeds 12 pkfma (R=6 reuse)
__device__ __forceinline__ void dot6_acc(const f32x4 (&wA0)[8], const f32x4 (&wA1)[8],
                                         const f32x4 (&wA2)[8], const f32x4 (&wB0)[8],
                                         const f32x4 (&wB1)[8], const f32x4 (&wB2)[8],
                                         const float* hb, int q,
                                         f32x2& cA0, f32x2& cA1, f32x2& cA2,
                                         f32x2& cB0, f32x2& cB1, f32x2& cB2) {
  const int base = 32 * q;
  #pragma unroll
  for (int r = 0; r < 8; ++r) {
    const int k = r ^ (q << 1);
    f32x4 h4 = *(const f32x4*)(hb + base + 4 * k);
    f32x2 hl = lo2(h4), hh = hi2(h4);
    pkfma(cA0, lo2(wA0[r]), hl); pkfma(cA0, hi2(wA0[r]), hh);
    pkfma(cA1, lo2(wA1[r]), hl); pkfma(cA1, hi2(wA1[r]), hh);
    pkfma(cA2, lo2(wA2[r]), hl); pkfma(cA2, hi2(wA2[r]), hh);
    pkfma(cB0, lo2(wB0[r]), hl); pkfma(cB0, hi2(wB0[r]), hh);
    pkfma(cB1, lo2(wB1[r]), hl); pkfma(cB1, hi2(wB1[r]), hh);
    pkfma(cB2, lo2(wB2[r]), hl); pkfma(cB2, hi2(wB2[r]), hh);
  }
}

// ===================== block 0: layer-0 recurrence (chunk c) =====================
__device__ __noinline__ void role_l0(const float* __restrict__ x,
                                     const float* __restrict__ w_ih0,
                                     const float* __restrict__ w_hh0,
                                     const float* __restrict__ b_ih0,
                                     const float* __restrict__ b_hh0,
                                     float* __restrict__ h0, int c) {
  __shared__ __align__(16) float hbuf[2][HDIM];
  const int tid = threadIdx.x, q = tid & 3, u = tid >> 2;
  f32x4 wA0[8], wA1[8], wA2[8], wB0[8], wB1[8], wB2[8];
  load_w3_pin(w_hh0, u, q, wA0, wA1, wA2);
  load_w3_pin(w_hh0, u + 64, q, wB0, wB1, wB2);
  // lane q handles x cols {2q,2q+1}; butterfly sums x-slices with the h-part
  f32x2 wxA0 = ld2_pin(w_ih0 + (size_t)u * 8 + 2 * q);
  f32x2 wxA1 = ld2_pin(w_ih0 + (size_t)(u + 128) * 8 + 2 * q);
  f32x2 wxA2 = ld2_pin(w_ih0 + (size_t)(u + 256) * 8 + 2 * q);
  f32x2 wxB0 = ld2_pin(w_ih0 + (size_t)(u + 64) * 8 + 2 * q);
  f32x2 wxB1 = ld2_pin(w_ih0 + (size_t)(u + 192) * 8 + 2 * q);
  f32x2 wxB2 = ld2_pin(w_ih0 + (size_t)(u + 320) * 8 + 2 * q);
  const float birA = ld1_pin(b_ih0 + u), bhrA = ld1_pin(b_hh0 + u);
  const float bizA = ld1_pin(b_ih0 + u + 128), bhzA = ld1_pin(b_hh0 + u + 128);
  const float binA = ld1_pin(b_ih0 + u + 256), bhnA = ld1_pin(b_hh0 + u + 256);
  const float birB = ld1_pin(b_ih0 + u + 64), bhrB = ld1_pin(b_hh0 + u + 64);
  const float bizB = ld1_pin(b_ih0 + u + 192), bhzB = ld1_pin(b_hh0 + u + 192);
  const float binB = ld1_pin(b_ih0 + u + 320), bhnB = ld1_pin(b_hh0 + u + 320);
  vwait();
  const float bsrA = birA + bhrA, bszA = bizA + bhzA;
  const float bsrB = birB + bhrB, bszB = bizB + bhzB;

  float hp0 = 0.f, hp1 = 0.f;
  if (c > 0) {
    hp0 = h0[((size_t)c * CH - 1) * HDIM + u];
    hp1 = h0[((size_t)c * CH - 1) * HDIM + u + 64];
  }
  if (q == 0) { hbuf[0][u] = hp0; hbuf[0][u + 64] = hp1; }
  const int t0 = c * CH;
  f32x2 xva = *(const f32x2*)(x + (size_t)t0 * 8 + 2 * q);
  f32x2 xvb = *(const f32x2*)(x + (size_t)(t0 + 1) * 8 + 2 * q);
  __syncthreads();

  for (int s2 = 0; s2 < CH / 2; ++s2) {
    const int t = t0 + 2 * s2;
    const int tp2 = (t + 2 < T_STEPS) ? t + 2 : T_STEPS - 1;  // clamped prefetch
    const int tp3 = (t + 3 < T_STEPS) ? t + 3 : T_STEPS - 1;
    f32x2 xn0 = *(const f32x2*)(x + (size_t)tp2 * 8 + 2 * q);
    f32x2 xn1 = *(const f32x2*)(x + (size_t)tp3 * 8 + 2 * q);
    #pragma unroll
    for (int pr = 0; pr < 2; ++pr) {   // two steps: parity 0 then 1
      f32x2 cA0 = {0.f, 0.f}, cA1 = {0.f, 0.f}, cA2 = {0.f, 0.f}, cA3 = {0.f, 0.f};
      f32x2 cB0 = {0.f, 0.f}, cB1 = {0.f, 0.f}, cB2 = {0.f, 0.f}, cB3 = {0.f, 0.f};
      const f32x2 xv = pr ? xvb : xva;
      pkfma(cA0, wxA0, xv); pkfma(cA1, wxA1, xv); pkfma(cA3, wxA2, xv);
      pkfma(cB0, wxB0, xv); pkfma(cB1, wxB1, xv); pkfma(cB3, wxB2, xv);
      dot6_acc(wA0, wA1, wA2, wB0, wB1, wB2, hbuf[pr], q,
               cA0, cA1, cA2, cB0, cB1, cB2);
      const float a0A = red4q(cA0.x + cA0.y), a1A = red4q(cA1.x + cA1.y);
      const float a2A = red4q(cA2.x + cA2.y), a3A = red4q(cA3.x + cA3.y);
      const float a0B = red4q(cB0.x + cB0.y), a1B = red4q(cB1.x + cB1.y);
      const float a2B = red4q(cB2.x + cB2.y), a3B = red4q(cB3.x + cB3.y);
      const float rrA = sigm(a0A + bsrA), zzA = sigm(a1A + bszA);
      const float nnA = tanh_fast((a3A + binA) + rrA * (a2A + bhnA));
      hp0 = (1.f - zzA) * nnA + zzA * hp0;
      const float rrB = sigm(a0B + bsrB), zzB = sigm(a1B + bszB);
      const float nnB = tanh_fast((a3B + binB) + rrB * (a2B + bhnB));
      hp1 = (1.f - zzB) * nnB + zzB * hp1;
      if (q == 0) {
        hbuf[pr ^ 1][u] = hp0;      hbuf[pr ^ 1][u + 64] = hp1;
        h0[(size_t)(t + pr) * HDIM + u] = hp0;
        h0[(size_t)(t + pr) * HDIM + u + 64] = hp1;
      }
      __syncthreads();
    }
    xva = xn0; xvb = xn1;
  }
}

// ===================== block 1: layer-1 recurrence (chunk c) =====================
__device__ __noinline__ void role_l1(const float* __restrict__ w_hh1,
                                     const float* __restrict__ b_hh1,
                                     const float* __restrict__ gi1s,  // ring slot base
                                     float* __restrict__ hstate1,
                                     float* __restrict__ out, int c) {
  __shared__ __align__(16) float hbuf[2][HDIM];
  __shared__ __align__(16) float sg[2][GS * 512];   // 2 x 16 KB gi1 staging
  const int tid = threadIdx.x, q = tid & 3, u = tid >> 2;
  f32x4 wA0[8], wA1[8], wA2[8], wB0[8], wB1[8], wB2[8];
  load_w3_pin(w_hh1, u, q, wA0, wA1, wA2);
  load_w3_pin(w_hh1, u + 64, q, wB0, wB1, wB2);
  const float bhrA_ = ld1_pin(b_hh1 + u), bhzA_ = ld1_pin(b_hh1 + u + 128);
  const float bhnA_ = ld1_pin(b_hh1 + u + 256);
  const float bhrB_ = ld1_pin(b_hh1 + u + 64), bhzB_ = ld1_pin(b_hh1 + u + 192);
  const float bhnB_ = ld1_pin(b_hh1 + u + 320);
  vwait();
  const float bhrA = bhrA_, bhzA = bhzA_, bhnA = bhnA_;
  const float bhrB = bhrB_, bhzB = bhzB_, bhnB = bhnB_;

  float hp0 = 0.f, hp1 = 0.f;
  if (c > 0) { hp0 = hstate1[u]; hp1 = hstate1[u + 64]; }
  if (q == 0) { hbuf[0][u] = hp0; hbuf[0][u + 64] = hp1; }
  {  // blocking preload of group 0 (16 KB, 4 f32x4 per thread)
    const f32x4* b4 = (const f32x4*)gi1s;
    #pragma unroll
    for (int k = 0; k < 4; ++k) ((f32x4*)sg[0])[tid + 256 * k] = b4[tid + 256 * k];
  }
  __syncthreads();

  int cur = 0;
  for (int g = 0; g < NGRP; ++g) {
    f32x4 pf[4];
    const bool hpf = (g + 1 < NGRP);
    if (hpf) {  // issue next group's loads early; LDS-write at s==GS-2
      const f32x4* b4 = (const f32x4*)(gi1s + (size_t)(g + 1) * GS * 512);
      #pragma unroll
      for (int k = 0; k < 4; ++k) pf[k] = b4[tid + 256 * k];
    }
    #pragma unroll
    for (int s = 0; s < GS; ++s) {
      const int pr = s & 1;
      f32x2 cA0 = {0.f, 0.f}, cA1 = {0.f, 0.f}, cA2 = {0.f, 0.f};
      f32x2 cB0 = {0.f, 0.f}, cB1 = {0.f, 0.f}, cB2 = {0.f, 0.f};
      dot6_acc(wA0, wA1, wA2, wB0, wB1, wB2, hbuf[pr], q,
               cA0, cA1, cA2, cB0, cB1, cB2);
      const float a0A = red4q(cA0.x + cA0.y), a1A = red4q(cA1.x + cA1.y);
      const float a2A = red4q(cA2.x + cA2.y);
      const float a0B = red4q(cB0.x + cB0.y), a1B = red4q(cB1.x + cB1.y);
      const float a2B = red4q(cB2.x + cB2.y);
      const f32x4 gvA = *(const f32x4*)&sg[cur][s * 512 + 4 * u];
      const f32x4 gvB = *(const f32x4*)&sg[cur][s * 512 + 4 * (u + 64)];
      if (s == GS - 2 && hpf) {
        #pragma unroll
        for (int k = 0; k < 4; ++k) ((f32x4*)sg[cur ^ 1])[tid + 256 * k] = pf[k];
      }
      const float rrA = sigm(gvA.x + a0A + bhrA), zzA = sigm(gvA.y + a1A + bhzA);
      const float nnA = tanh_fast(gvA.z + rrA * (a2A + bhnA));
      hp0 = (1.f - zzA) * nnA + zzA * hp0;
      const float rrB = sigm(gvB.x + a0B + bhrB), zzB = sigm(gvB.y + a1B + bhzB);
      const float nnB = tanh_fast(gvB.z + rrB * (a2B + bhnB));
      hp1 = (1.f - zzB) * nnB + zzB * hp1;
      if (q == 0) { hbuf[pr ^ 1][u] = hp0; hbuf[pr ^ 1][u + 64] = hp1; }
      __syncthreads();
    }
    cur ^= 1;
  }
  if (q == 0) {
    hstate1[u] = hp0; hstate1[u + 64] = hp1;
    out[u] = hp0;     out[u + 64] = hp1;
  }
}

// ========== blocks 2..4: gi1[t] = w_ih1 @ h0[t] + b_ih1 (one gate block each) ==========
__device__ __noinline__ void role_army(const float* __restrict__ h0c,
                                       const float* __restrict__ w_ih1,
                                       const float* __restrict__ b_ih1,
                                       float* __restrict__ gi1s, int rb) {
  __shared__ __align__(16) float hsg[2][GS * HDIM];  // 2 x 4 KB h0 staging
  const int tid = threadIdx.x, q = tid & 3, u = tid >> 2;
  const int rowA = rb * HDIM + u, rowB = rb * HDIM + u + 64;
  f32x4 wA[8], wB[8];
  #pragma unroll
  for (int r = 0; r < 8; ++r) {
    const int col = 32 * q + 4 * (r ^ (q << 1));
    wA[r] = ld4_pin(w_ih1 + (size_t)rowA * 128 + col);
    wB[r] = ld4_pin(w_ih1 + (size_t)rowB * 128 + col);
  }
  const float bA_ = ld1_pin(b_ih1 + rowA), bB_ = ld1_pin(b_ih1 + rowB);
  vwait();
  const float bA = bA_, bB = bB_;

  ((f32x4*)hsg[0])[tid] = ((const f32x4*)h0c)[tid];
  __syncthreads();

  int cur = 0;
  for (int g = 0; g < NGRP; ++g) {
    f32x4 pf;
    const bool hpf = (g + 1 < NGRP);
    if (hpf) pf = ((const f32x4*)(h0c + (size_t)(g + 1) * GS * HDIM))[tid];
    #pragma unroll
    for (int s = 0; s < GS; ++s) {
      f32x2 cA = {0.f, 0.f}, cB = {0.f, 0.f};
      const float* hb = hsg[cur] + s * HDIM + 32 * q;
      #pragma unroll
      for (int r = 0; r < 8; ++r) {
        f32x4 h4 = *(const f32x4*)(hb + 4 * (r ^ (q << 1)));
        pkfma(cA, lo2(wA[r]), lo2(h4)); pkfma(cA, hi2(wA[r]), hi2(h4));
        pkfma(cB, lo2(wB[r]), lo2(h4)); pkfma(cB, hi2(wB[r]), hi2(h4));
      }
      const float aA = red4q(cA.x + cA.y);
      const float aB = red4q(cB.x + cB.y);
      if (q == 0) {
        gi1s[(size_t)(g * GS + s) * 512 + 4 * u + rb] = aA + bA;
        gi1s[(size_t)(g * GS + s) * 512 + 4 * (u + 64) + rb] = aB + bB;
      }
    }
    if (hpf) ((f32x4*)hsg[cur ^ 1])[tid] = pf;
    __syncthreads();  // one barrier per group: guards hsg swap
    cur ^= 1;
  }
}

__global__ __attribute__((amdgpu_flat_work_group_size(256, 256),
                          amdgpu_waves_per_eu(1, 1)))
void gru_pipe(const float* __restrict__ x,
              const float* __restrict__ w_ih0, const float* __restrict__ w_hh0,
              const float* __restrict__ b_ih0, const float* __restrict__ b_hh0,
              const float* __restrict__ w_ih1, const float* __restrict__ w_hh1,
              const float* __restrict__ b_ih1, const float* __restrict__ b_hh1,
              float* __restrict__ out, float* __restrict__ h0,
              float* __restrict__ gi1_ring, float* __restrict__ hstate1, int k) {
  const int bid = blockIdx.x;
  if (bid == 0) {
    if (k < NC)
      role_l0(x, w_ih0, w_hh0, b_ih0, b_hh0, h0, k);
  } else if (bid == 1) {
    if (k >= 2)
      role_l1(w_hh1, b_hh1, gi1_ring + (size_t)((k - 2) & 1) * CH * 512,
              hstate1, out, k - 2);
  } else {
    const int c = k - 1;
    if (c >= 0 && c < NC)
      role_army(h0 + (size_t)c * CH * HDIM, w_ih1, b_ih1,
                gi1_ring + (size_t)(c & 1) * CH * 512, bid - 2);
  }
}

extern "C" void kernel_launch(void* const* d_in, const int* in_sizes, int n_in,
                              void* d_out, int out_size, void* d_ws, size_t ws_size,
                              hipStream_t stream) {
  (void)in_sizes; (void)n_in; (void)out_size; (void)ws_size;
  const float* x     = (const float*)d_in[0];
  const float* w_ih0 = (const float*)d_in[1];
  const float* w_hh0 = (const float*)d_in[2];
  const float* b_ih0 = (const float*)d_in[3];
  const float* b_hh0 = (const float*)d_in[4];
  const float* w_ih1 = (const float*)d_in[5];
  const float* w_hh1 = (const float*)d_in[6];
  const float* b_ih1 = (const float*)d_in[7];
  const float* b_hh1 = (const float*)d_in[8];
  float* out = (float*)d_out;

  // ws: h0 full sequence (16 MB) | gi1 2-chunk ring (4 MB) | hstate1 (512 B)
  float* h0       = (float*)d_ws;
  float* gi1_ring = h0 + (size_t)T_STEPS * HDIM;
  float* hstate1  = gi1_ring + (size_t)2 * CH * 512;

  for (int k = 0; k <= NC + 1; ++k) {
    hipLaunchKernelGGL(gru_pipe, dim3(5), dim3(256), 0, stream,
                       x, w_ih0, w_hh0, b_ih0, b_hh0,
                       w_ih1, w_hh1, b_ih1, b_hh1, out,
                       h0, gi1_ring, hstate1, k);
  }
}

// Round 9
// 24917.422 us; speedup vs baseline: 1.0995x; 1.0995x over previous
//
#include <hip/hip_runtime.h>

// 2-layer GRU, I=8, H=128, T=32768 sequential steps, out = final h1 (128 f32).
// LAUNCH-LEVEL pipeline (no flags, no spins): launch k runs, as disjoint blocks,
//   block 0   : layer-0 recurrence, chunk k        (writes h0[chunk k])
//   blocks2-4 : gi1 = w_ih1@h0 + b_ih1, chunk k-1  (reads h0, writes gi1 ring)
//   block 1   : layer-1 recurrence, chunk k-2      (reads gi1 ring, writes out)
// Stream order between launches = implicit release/acquire; zero deadlock surface.
//
// r8 lesson: __noinline__ role functions are register-allocated WITHOUT the
// kernel's waves_per_eu attribute -> RA targets default occupancy (~128 VGPR)
// and SPILLS the 192 pinned weight registers to scratch (r7 VGPR=124, r8=144).
// Fix: __forceinline__ everything into the kernel carrying waves_per_eu(1,1)
// -> 512-VGPR budget, weights truly resident. FP math bit-identical to r8
// (which passed absmax 0.0).

#define T_STEPS 32768
#define HDIM 128
#define GS 8
#define CH 1024                 // steps per chunk
#define NC (T_STEPS / CH)       // 32 chunks
#define NGRP (CH / GS)          // groups per chunk

typedef __attribute__((ext_vector_type(2))) float f32x2;
typedef __attribute__((ext_vector_type(4))) float f32x4;

__device__ __forceinline__ f32x2 lo2(f32x4 v) { return __builtin_shufflevector(v, v, 0, 1); }
__device__ __forceinline__ f32x2 hi2(f32x4 v) { return __builtin_shufflevector(v, v, 2, 3); }
__device__ __forceinline__ void pkfma(f32x2& acc, f32x2 a, f32x2 b) {
  asm("v_pk_fma_f32 %0, %1, %2, %0" : "+v"(acc) : "v"(a), "v"(b));
}
__device__ __forceinline__ float sigm(float x) {
  return __fdividef(1.f, 1.f + __expf(-x));
}
__device__ __forceinline__ float tanh_fast(float x) {
  x = fminf(15.f, fmaxf(-15.f, x));
  float e = __expf(2.f * x);
  return (e - 1.f) * __fdividef(1.f, e + 1.f);
}
// quad butterfly (xor1 then xor2 via DPP quad_perm); proven r6-r8 (absmax 0.0)
__device__ __forceinline__ float red4q(float v) {
  int t = __builtin_amdgcn_mov_dpp(__builtin_bit_cast(int, v), 0xB1, 0xF, 0xF, true);
  v += __builtin_bit_cast(float, t);
  t = __builtin_amdgcn_mov_dpp(__builtin_bit_cast(int, v), 0x4E, 0xF, 0xF, true);
  v += __builtin_bit_cast(float, t);
  return v;
}
// Pinned loads: asm results cannot be rematerialized.
__device__ __forceinline__ f32x4 ld4_pin(const float* p) {
  f32x4 v;
  asm volatile("global_load_dwordx4 %0, %1, off" : "=v"(v) : "v"(p));
  return v;
}
__device__ __forceinline__ f32x2 ld2_pin(const float* p) {
  f32x2 v;
  asm volatile("global_load_dwordx2 %0, %1, off" : "=v"(v) : "v"(p));
  return v;
}
__device__ __forceinline__ float ld1_pin(const float* p) {
  float v;
  asm volatile("global_load_dword %0, %1, off" : "=v"(v) : "v"(p));
  return v;
}
__device__ __forceinline__ void vwait() {
  asm volatile("s_waitcnt vmcnt(0)" ::: "memory");
}

// Thread t (256/block): q=t&3 (32-col chunk), u=t>>2 in [0,64) -> units u, u+64.
// Weights PRE-ROTATED: slot r holds quad k=r^2q -> 4 q-lanes hit 4 disjoint
// bank-quads per read (broadcast across unit-groups), conflict-free (PMC=0).
__device__ __forceinline__ void load_w3_pin(const float* __restrict__ W, int row0,
                                            int q, f32x4 (&w0)[8], f32x4 (&w1)[8],
                                            f32x4 (&w2)[8]) {
  #pragma unroll
  for (int r = 0; r < 8; ++r) {
    const int k = r ^ (q << 1);
    const int col = 32 * q + 4 * k;
    w0[r] = ld4_pin(W + (size_t)row0 * 128 + col);
    w1[r] = ld4_pin(W + (size_t)(row0 + 128) * 128 + col);
    w2[r] = ld4_pin(W + (size_t)(row0 + 256) * 128 + col);
  }
}

// h-part for 6 rows (2 units x 3 gates): each h4 read feeds 12 pkfma (R=6 reuse)
__device__ __forceinline__ void dot6_acc(const f32x4 (&wA0)[8], const f32x4 (&wA1)[8],
                                         const f32x4 (&wA2)[8], const f32x4 (&wB0)[8],
                                         const f32x4 (&wB1)[8], const f32x4 (&wB2)[8],
                                         const float* hb, int q,
                                         f32x2& cA0, f32x2& cA1, f32x2& cA2,
                                         f32x2& cB0, f32x2& cB1, f32x2& cB2) {
  const int base = 32 * q;
  #pragma unroll
  for (int r = 0; r < 8; ++r) {
    const int k = r ^ (q << 1);
    f32x4 h4 = *(const f32x4*)(hb + base + 4 * k);
    f32x2 hl = lo2(h4), hh = hi2(h4);
    pkfma(cA0, lo2(wA0[r]), hl); pkfma(cA0, hi2(wA0[r]), hh);
    pkfma(cA1, lo2(wA1[r]), hl); pkfma(cA1, hi2(wA1[r]), hh);
    pkfma(cA2, lo2(wA2[r]), hl); pkfma(cA2, hi2(wA2[r]), hh);
    pkfma(cB0, lo2(wB0[r]), hl); pkfma(cB0, hi2(wB0[r]), hh);
    pkfma(cB1, lo2(wB1[r]), hl); pkfma(cB1, hi2(wB1[r]), hh);
    pkfma(cB2, lo2(wB2[r]), hl); pkfma(cB2, hi2(wB2[r]), hh);
  }
}

// ===================== block 0: layer-0 recurrence (chunk c) =====================
__device__ __forceinline__ void role_l0(const float* __restrict__ x,
                                        const float* __restrict__ w_ih0,
                                        const float* __restrict__ w_hh0,
                                        const float* __restrict__ b_ih0,
                                        const float* __restrict__ b_hh0,
                                        float* __restrict__ h0, int c) {
  __shared__ __align__(16) float hbuf[2][HDIM];
  const int tid = threadIdx.x, q = tid & 3, u = tid >> 2;
  f32x4 wA0[8], wA1[8], wA2[8], wB0[8], wB1[8], wB2[8];
  load_w3_pin(w_hh0, u, q, wA0, wA1, wA2);
  load_w3_pin(w_hh0, u + 64, q, wB0, wB1, wB2);
  // lane q handles x cols {2q,2q+1}; butterfly sums x-slices with the h-part
  f32x2 wxA0 = ld2_pin(w_ih0 + (size_t)u * 8 + 2 * q);
  f32x2 wxA1 = ld2_pin(w_ih0 + (size_t)(u + 128) * 8 + 2 * q);
  f32x2 wxA2 = ld2_pin(w_ih0 + (size_t)(u + 256) * 8 + 2 * q);
  f32x2 wxB0 = ld2_pin(w_ih0 + (size_t)(u + 64) * 8 + 2 * q);
  f32x2 wxB1 = ld2_pin(w_ih0 + (size_t)(u + 192) * 8 + 2 * q);
  f32x2 wxB2 = ld2_pin(w_ih0 + (size_t)(u + 320) * 8 + 2 * q);
  const float birA = ld1_pin(b_ih0 + u), bhrA = ld1_pin(b_hh0 + u);
  const float bizA = ld1_pin(b_ih0 + u + 128), bhzA = ld1_pin(b_hh0 + u + 128);
  const float binA = ld1_pin(b_ih0 + u + 256), bhnA = ld1_pin(b_hh0 + u + 256);
  const float birB = ld1_pin(b_ih0 + u + 64), bhrB = ld1_pin(b_hh0 + u + 64);
  const float bizB = ld1_pin(b_ih0 + u + 192), bhzB = ld1_pin(b_hh0 + u + 192);
  const float binB = ld1_pin(b_ih0 + u + 320), bhnB = ld1_pin(b_hh0 + u + 320);
  vwait();
  const float bsrA = birA + bhrA, bszA = bizA + bhzA;
  const float bsrB = birB + bhrB, bszB = bizB + bhzB;

  float hp0 = 0.f, hp1 = 0.f;
  if (c > 0) {
    hp0 = h0[((size_t)c * CH - 1) * HDIM + u];
    hp1 = h0[((size_t)c * CH - 1) * HDIM + u + 64];
  }
  if (q == 0) { hbuf[0][u] = hp0; hbuf[0][u + 64] = hp1; }
  const int t0 = c * CH;
  f32x2 xva = *(const f32x2*)(x + (size_t)t0 * 8 + 2 * q);
  f32x2 xvb = *(const f32x2*)(x + (size_t)(t0 + 1) * 8 + 2 * q);
  __syncthreads();

  for (int s2 = 0; s2 < CH / 2; ++s2) {
    const int t = t0 + 2 * s2;
    const int tp2 = (t + 2 < T_STEPS) ? t + 2 : T_STEPS - 1;  // clamped prefetch
    const int tp3 = (t + 3 < T_STEPS) ? t + 3 : T_STEPS - 1;
    f32x2 xn0 = *(const f32x2*)(x + (size_t)tp2 * 8 + 2 * q);
    f32x2 xn1 = *(const f32x2*)(x + (size_t)tp3 * 8 + 2 * q);
    #pragma unroll
    for (int pr = 0; pr < 2; ++pr) {   // two steps: parity 0 then 1
      f32x2 cA0 = {0.f, 0.f}, cA1 = {0.f, 0.f}, cA2 = {0.f, 0.f}, cA3 = {0.f, 0.f};
      f32x2 cB0 = {0.f, 0.f}, cB1 = {0.f, 0.f}, cB2 = {0.f, 0.f}, cB3 = {0.f, 0.f};
      const f32x2 xv = pr ? xvb : xva;
      pkfma(cA0, wxA0, xv); pkfma(cA1, wxA1, xv); pkfma(cA3, wxA2, xv);
      pkfma(cB0, wxB0, xv); pkfma(cB1, wxB1, xv); pkfma(cB3, wxB2, xv);
      dot6_acc(wA0, wA1, wA2, wB0, wB1, wB2, hbuf[pr], q,
               cA0, cA1, cA2, cB0, cB1, cB2);
      const float a0A = red4q(cA0.x + cA0.y), a1A = red4q(cA1.x + cA1.y);
      const float a2A = red4q(cA2.x + cA2.y), a3A = red4q(cA3.x + cA3.y);
      const float a0B = red4q(cB0.x + cB0.y), a1B = red4q(cB1.x + cB1.y);
      const float a2B = red4q(cB2.x + cB2.y), a3B = red4q(cB3.x + cB3.y);
      const float rrA = sigm(a0A + bsrA), zzA = sigm(a1A + bszA);
      const float nnA = tanh_fast((a3A + binA) + rrA * (a2A + bhnA));
      hp0 = (1.f - zzA) * nnA + zzA * hp0;
      const float rrB = sigm(a0B + bsrB), zzB = sigm(a1B + bszB);
      const float nnB = tanh_fast((a3B + binB) + rrB * (a2B + bhnB));
      hp1 = (1.f - zzB) * nnB + zzB * hp1;
      if (q == 0) {
        hbuf[pr ^ 1][u] = hp0;      hbuf[pr ^ 1][u + 64] = hp1;
        h0[(size_t)(t + pr) * HDIM + u] = hp0;
        h0[(size_t)(t + pr) * HDIM + u + 64] = hp1;
      }
      __syncthreads();
    }
    xva = xn0; xvb = xn1;
  }
}

// ===================== block 1: layer-1 recurrence (chunk c) =====================
__device__ __forceinline__ void role_l1(const float* __restrict__ w_hh1,
                                        const float* __restrict__ b_hh1,
                                        const float* __restrict__ gi1s,  // ring slot
                                        float* __restrict__ hstate1,
                                        float* __restrict__ out, int c) {
  __shared__ __align__(16) float hbuf[2][HDIM];
  __shared__ __align__(16) float sg[2][GS * 512];   // 2 x 16 KB gi1 staging
  const int tid = threadIdx.x, q = tid & 3, u = tid >> 2;
  f32x4 wA0[8], wA1[8], wA2[8], wB0[8], wB1[8], wB2[8];
  load_w3_pin(w_hh1, u, q, wA0, wA1, wA2);
  load_w3_pin(w_hh1, u + 64, q, wB0, wB1, wB2);
  const float bhrA_ = ld1_pin(b_hh1 + u), bhzA_ = ld1_pin(b_hh1 + u + 128);
  const float bhnA_ = ld1_pin(b_hh1 + u + 256);
  const float bhrB_ = ld1_pin(b_hh1 + u + 64), bhzB_ = ld1_pin(b_hh1 + u + 192);
  const float bhnB_ = ld1_pin(b_hh1 + u + 320);
  vwait();
  const float bhrA = bhrA_, bhzA = bhzA_, bhnA = bhnA_;
  const float bhrB = bhrB_, bhzB = bhzB_, bhnB = bhnB_;

  float hp0 = 0.f, hp1 = 0.f;
  if (c > 0) { hp0 = hstate1[u]; hp1 = hstate1[u + 64]; }
  if (q == 0) { hbuf[0][u] = hp0; hbuf[0][u + 64] = hp1; }
  {  // blocking preload of group 0 (16 KB, 4 f32x4 per thread)
    const f32x4* b4 = (const f32x4*)gi1s;
    #pragma unroll
    for (int k = 0; k < 4; ++k) ((f32x4*)sg[0])[tid + 256 * k] = b4[tid + 256 * k];
  }
  __syncthreads();

  int cur = 0;
  for (int g = 0; g < NGRP; ++g) {
    f32x4 pf[4];
    const bool hpf = (g + 1 < NGRP);
    if (hpf) {  // issue next group's loads early; LDS-write at s==GS-2
      const f32x4* b4 = (const f32x4*)(gi1s + (size_t)(g + 1) * GS * 512);
      #pragma unroll
      for (int k = 0; k < 4; ++k) pf[k] = b4[tid + 256 * k];
    }
    #pragma unroll
    for (int s = 0; s < GS; ++s) {
      const int pr = s & 1;
      f32x2 cA0 = {0.f, 0.f}, cA1 = {0.f, 0.f}, cA2 = {0.f, 0.f};
      f32x2 cB0 = {0.f, 0.f}, cB1 = {0.f, 0.f}, cB2 = {0.f, 0.f};
      dot6_acc(wA0, wA1, wA2, wB0, wB1, wB2, hbuf[pr], q,
               cA0, cA1, cA2, cB0, cB1, cB2);
      const float a0A = red4q(cA0.x + cA0.y), a1A = red4q(cA1.x + cA1.y);
      const float a2A = red4q(cA2.x + cA2.y);
      const float a0B = red4q(cB0.x + cB0.y), a1B = red4q(cB1.x + cB1.y);
      const float a2B = red4q(cB2.x + cB2.y);
      const f32x4 gvA = *(const f32x4*)&sg[cur][s * 512 + 4 * u];
      const f32x4 gvB = *(const f32x4*)&sg[cur][s * 512 + 4 * (u + 64)];
      if (s == GS - 2 && hpf) {
        #pragma unroll
        for (int k = 0; k < 4; ++k) ((f32x4*)sg[cur ^ 1])[tid + 256 * k] = pf[k];
      }
      const float rrA = sigm(gvA.x + a0A + bhrA), zzA = sigm(gvA.y + a1A + bhzA);
      const float nnA = tanh_fast(gvA.z + rrA * (a2A + bhnA));
      hp0 = (1.f - zzA) * nnA + zzA * hp0;
      const float rrB = sigm(gvB.x + a0B + bhrB), zzB = sigm(gvB.y + a1B + bhzB);
      const float nnB = tanh_fast(gvB.z + rrB * (a2B + bhnB));
      hp1 = (1.f - zzB) * nnB + zzB * hp1;
      if (q == 0) { hbuf[pr ^ 1][u] = hp0; hbuf[pr ^ 1][u + 64] = hp1; }
      __syncthreads();
    }
    cur ^= 1;
  }
  if (q == 0) {
    hstate1[u] = hp0; hstate1[u + 64] = hp1;
    out[u] = hp0;     out[u + 64] = hp1;
  }
}

// ========== blocks 2..4: gi1[t] = w_ih1 @ h0[t] + b_ih1 (one gate block each) ==========
__device__ __forceinline__ void role_army(const float* __restrict__ h0c,
                                          const float* __restrict__ w_ih1,
                                          const float* __restrict__ b_ih1,
                                          float* __restrict__ gi1s, int rb) {
  __shared__ __align__(16) float hsg[2][GS * HDIM];  // 2 x 4 KB h0 staging
  const int tid = threadIdx.x, q = tid & 3, u = tid >> 2;
  const int rowA = rb * HDIM + u, rowB = rb * HDIM + u + 64;
  f32x4 wA[8], wB[8];
  #pragma unroll
  for (int r = 0; r < 8; ++r) {
    const int col = 32 * q + 4 * (r ^ (q << 1));
    wA[r] = ld4_pin(w_ih1 + (size_t)rowA * 128 + col);
    wB[r] = ld4_pin(w_ih1 + (size_t)rowB * 128 + col);
  }
  const float bA_ = ld1_pin(b_ih1 + rowA), bB_ = ld1_pin(b_ih1 + rowB);
  vwait();
  const float bA = bA_, bB = bB_;

  ((f32x4*)hsg[0])[tid] = ((const f32x4*)h0c)[tid];
  __syncthreads();

  int cur = 0;
  for (int g = 0; g < NGRP; ++g) {
    f32x4 pf;
    const bool hpf = (g + 1 < NGRP);
    if (hpf) pf = ((const f32x4*)(h0c + (size_t)(g + 1) * GS * HDIM))[tid];
    #pragma unroll
    for (int s = 0; s < GS; ++s) {
      f32x2 cA = {0.f, 0.f}, cB = {0.f, 0.f};
      const float* hb = hsg[cur] + s * HDIM + 32 * q;
      #pragma unroll
      for (int r = 0; r < 8; ++r) {
        f32x4 h4 = *(const f32x4*)(hb + 4 * (r ^ (q << 1)));
        pkfma(cA, lo2(wA[r]), lo2(h4)); pkfma(cA, hi2(wA[r]), hi2(h4));
        pkfma(cB, lo2(wB[r]), lo2(h4)); pkfma(cB, hi2(wB[r]), hi2(h4));
      }
      const float aA = red4q(cA.x + cA.y);
      const float aB = red4q(cB.x + cB.y);
      if (q == 0) {
        gi1s[(size_t)(g * GS + s) * 512 + 4 * u + rb] = aA + bA;
        gi1s[(size_t)(g * GS + s) * 512 + 4 * (u + 64) + rb] = aB + bB;
      }
    }
    if (hpf) ((f32x4*)hsg[cur ^ 1])[tid] = pf;
    __syncthreads();  // one barrier per group: guards hsg swap
    cur ^= 1;
  }
}

__global__ __attribute__((amdgpu_flat_work_group_size(256, 256),
                          amdgpu_waves_per_eu(1, 1)))
void gru_pipe(const float* __restrict__ x,
              const float* __restrict__ w_ih0, const float* __restrict__ w_hh0,
              const float* __restrict__ b_ih0, const float* __restrict__ b_hh0,
              const float* __restrict__ w_ih1, const float* __restrict__ w_hh1,
              const float* __restrict__ b_ih1, const float* __restrict__ b_hh1,
              float* __restrict__ out, float* __restrict__ h0,
              float* __restrict__ gi1_ring, float* __restrict__ hstate1, int k) {
  const int bid = blockIdx.x;
  if (bid == 0) {
    if (k < NC)
      role_l0(x, w_ih0, w_hh0, b_ih0, b_hh0, h0, k);
  } else if (bid == 1) {
    if (k >= 2)
      role_l1(w_hh1, b_hh1, gi1_ring + (size_t)((k - 2) & 1) * CH * 512,
              hstate1, out, k - 2);
  } else {
    const int c = k - 1;
    if (c >= 0 && c < NC)
      role_army(h0 + (size_t)c * CH * HDIM, w_ih1, b_ih1,
                gi1_ring + (size_t)(c & 1) * CH * 512, bid - 2);
  }
}

extern "C" void kernel_launch(void* const* d_in, const int* in_sizes, int n_in,
                              void* d_out, int out_size, void* d_ws, size_t ws_size,
                              hipStream_t stream) {
  (void)in_sizes; (void)n_in; (void)out_size; (void)ws_size;
  const float* x     = (const float*)d_in[0];
  const float* w_ih0 = (const float*)d_in[1];
  const float* w_hh0 = (const float*)d_in[2];
  const float* b_ih0 = (const float*)d_in[3];
  const float* b_hh0 = (const float*)d_in[4];
  const float* w_ih1 = (const float*)d_in[5];
  const float* w_hh1 = (const float*)d_in[6];
  const float* b_ih1 = (const float*)d_in[7];
  const float* b_hh1 = (const float*)d_in[8];
  float* out = (float*)d_out;

  // ws: h0 full sequence (16 MB) | gi1 2-chunk ring (4 MB) | hstate1 (512 B)
  float* h0       = (float*)d_ws;
  float* gi1_ring = h0 + (size_t)T_STEPS * HDIM;
  float* hstate1  = gi1_ring + (size_t)2 * CH * 512;

  for (int k = 0; k <= NC + 1; ++k) {
    hipLaunchKernelGGL(gru_pipe, dim3(5), dim3(256), 0, stream,
                       x, w_ih0, w_hh0, b_ih0, b_hh0,
                       w_ih1, w_hh1, b_ih1, b_hh1, out,
                       h0, gi1_ring, hstate1, k);
  }
}